// Round 9
// baseline (206.597 us; speedup 1.0000x reference)
//
#include <hip/hip_runtime.h>

// SE_loss_w_threshold: h,v (8,16384,128) fp32, N scalar.
// out[0]=mean(Rp), out[1..8]=R_per_user_p, out[9]=sum(R_per_user_p)
//
// v9 = v7 + 2-batch-per-wave INTERLEAVE (ILP doubling).
//   v1/v7/v8 post-mortem: ~50us wall is invariant under occupancy 30-50%,
//   LDS-op count, reg/DMA pipelining, and even full L3 residency (v7/v8
//   replay dispatches: 131KB traffic, same 50us). No pipe saturated
//   (VALU 25%, LDS ~47%) => latency-bound on each wave's serial chain
//   {stage -> lgkm -> 256-FMA dot chain -> 10 serial bpermutes -> log/exp}.
//   TLP is exhausted; the untried axis is per-wave ILP: the wave's two
//   batches are fully independent, so process them interleaved in one
//   pass -- 2x independent chains on every pipe at constant overhead,
//   constant LDS/block (37KB -> same 4 blocks/CU), constant grid.
//   Expected new wall: LDS pipe ~90% busy => ~25-30us.
//   Register safety: all loads transient inside one phase (the v4/v6
//   spill trap was values carried ACROSS the k-loop; none here).
// Per-batch accumulation orders (staging pattern, k ascending 0..63,
// nsq t-order, reduction trees, R-sum order b0 then b1) identical to v7
// => absmax 0.0 expected.

constexpr int U_    = 8;
constexpr int B_    = 16384;
constexpr int NT_   = 128;
constexpr int NBLK_ = 2048;
constexpr int WPB_  = 4;              // waves per block (256 threads)
constexpr int TW_   = NBLK_ * WPB_;   // 8192 waves; 2 batches per wave
constexpr int RS_   = 36;             // LDS plane-row stride (floats), 16B-aligned
constexpr float T_THRESH = 0.3f;
constexpr float LOG2_10  = 3.3219280948873623f;

__device__ __forceinline__ float hw_log2(float x) { return __builtin_amdgcn_logf(x); }
__device__ __forceinline__ float hw_exp2(float x) { return __builtin_amdgcn_exp2f(x); }

__global__ __launch_bounds__(256, 4) void se_main(const float* __restrict__ h,
                                                  const float* __restrict__ vv,
                                                  const float* __restrict__ Np,
                                                  float* __restrict__ partial) {
    // Per-wave PRIVATE tiles: [batch 0/1][h/v][16 plane-rows][RS_].
    // plane-row = 2*user + {0:re,1:im}; 32 floats used + 4 pad.
    // Wave-private => no __syncthreads in the loop (lgkmcnt orders
    // same-wave ds_write -> ds_read; v1/v7-proven).
    __shared__ float lds[WPB_][2][2][16 * RS_];
    __shared__ float red_f[WPB_];
    __shared__ float red_R[WPB_][U_];

    const int tid  = threadIdx.x;
    const int wave = tid >> 6;
    const int lane = tid & 63;
    const int ui   = lane >> 3;   // user i (row of A); also staging row
    const int uj   = lane & 7;    // user j (col of A); also staging float4-col
    const float Nval = Np[0];

    float* hb0 = lds[wave][0][0];
    float* vb0 = lds[wave][0][1];
    float* hb1 = lds[wave][1][0];
    float* vb1 = lds[wave][1][1];

    const int gwave = blockIdx.x * WPB_ + wave;
    const int b0 = gwave;             // batch 0 (== v7's it=0)
    const int b1 = gwave + TW_;       // batch 1 (== v7's it=1)

    // Per-lane global row base for staging: row = ui, float4-col = uj.
    const float* hrb = h  + (size_t)ui * ((size_t)B_ * NT_) + uj * 4;
    const float* vrb = vv + (size_t)ui * ((size_t)B_ * NT_) + uj * 4;

    float lane_sumR = 0.0f;
    float lane_sumf = 0.0f;

    float nsq0 = 0.0f, are0 = 0.0f, aim0 = 0.0f;
    float nsq1 = 0.0f, are1 = 0.0f, aim1 = 0.0f;

    #pragma unroll
    for (int x = 0; x < 2; ++x) {
        // ---- transient staging: both batches' k-half tiles ----
        // x=0: re half at [0,32), im half at [64,96); x=1: [32,64)/[96,128)
        {
            const int off = b0 * NT_ + x * 32;
            const float4 rh0 = *reinterpret_cast<const float4*>(hrb + off);
            const float4 rh1 = *reinterpret_cast<const float4*>(hrb + off + 64);
            const float4 rv0 = *reinterpret_cast<const float4*>(vrb + off);
            const float4 rv1 = *reinterpret_cast<const float4*>(vrb + off + 64);
            *reinterpret_cast<float4*>(&hb0[(2 * ui + 0) * RS_ + uj * 4]) = rh0;
            *reinterpret_cast<float4*>(&hb0[(2 * ui + 1) * RS_ + uj * 4]) = rh1;
            *reinterpret_cast<float4*>(&vb0[(2 * ui + 0) * RS_ + uj * 4]) = rv0;
            *reinterpret_cast<float4*>(&vb0[(2 * ui + 1) * RS_ + uj * 4]) = rv1;
            nsq0 += rv0.x * rv0.x + rv0.y * rv0.y + rv0.z * rv0.z + rv0.w * rv0.w
                  + rv1.x * rv1.x + rv1.y * rv1.y + rv1.z * rv1.z + rv1.w * rv1.w;
        }
        {
            const int off = b1 * NT_ + x * 32;
            const float4 rh0 = *reinterpret_cast<const float4*>(hrb + off);
            const float4 rh1 = *reinterpret_cast<const float4*>(hrb + off + 64);
            const float4 rv0 = *reinterpret_cast<const float4*>(vrb + off);
            const float4 rv1 = *reinterpret_cast<const float4*>(vrb + off + 64);
            *reinterpret_cast<float4*>(&hb1[(2 * ui + 0) * RS_ + uj * 4]) = rh0;
            *reinterpret_cast<float4*>(&hb1[(2 * ui + 1) * RS_ + uj * 4]) = rh1;
            *reinterpret_cast<float4*>(&vb1[(2 * ui + 0) * RS_ + uj * 4]) = rv0;
            *reinterpret_cast<float4*>(&vb1[(2 * ui + 1) * RS_ + uj * 4]) = rv1;
            nsq1 += rv0.x * rv0.x + rv0.y * rv0.y + rv0.z * rv0.z + rv0.w * rv0.w
                  + rv1.x * rv1.x + rv1.y * rv1.y + rv1.z * rv1.z + rv1.w * rv1.w;
        }

        // ---- A[i][j] partials, both batches interleaved (k ascending) ----
        const float* hre0 = &hb0[(2 * ui) * RS_];
        const float* vre0 = &vb0[(2 * uj) * RS_];
        const float* hre1 = &hb1[(2 * ui) * RS_];
        const float* vre1 = &vb1[(2 * uj) * RS_];
        #pragma unroll
        for (int ks = 0; ks < 32; ks += 4) {
            {
                const float4 hr = *reinterpret_cast<const float4*>(hre0 + ks);
                const float4 hi = *reinterpret_cast<const float4*>(hre0 + RS_ + ks);
                const float4 vr = *reinterpret_cast<const float4*>(vre0 + ks);
                const float4 vi = *reinterpret_cast<const float4*>(vre0 + RS_ + ks);
                are0 += hr.x * vr.x + hi.x * vi.x;
                aim0 += hi.x * vr.x - hr.x * vi.x;
                are0 += hr.y * vr.y + hi.y * vi.y;
                aim0 += hi.y * vr.y - hr.y * vi.y;
                are0 += hr.z * vr.z + hi.z * vi.z;
                aim0 += hi.z * vr.z - hr.z * vi.z;
                are0 += hr.w * vr.w + hi.w * vi.w;
                aim0 += hi.w * vr.w - hr.w * vi.w;
            }
            {
                const float4 hr = *reinterpret_cast<const float4*>(hre1 + ks);
                const float4 hi = *reinterpret_cast<const float4*>(hre1 + RS_ + ks);
                const float4 vr = *reinterpret_cast<const float4*>(vre1 + ks);
                const float4 vi = *reinterpret_cast<const float4*>(vre1 + RS_ + ks);
                are1 += hr.x * vr.x + hi.x * vi.x;
                aim1 += hi.x * vr.x - hr.x * vi.x;
                are1 += hr.y * vr.y + hi.y * vi.y;
                aim1 += hi.y * vr.y - hr.y * vi.y;
                are1 += hr.z * vr.z + hi.z * vi.z;
                aim1 += hi.z * vr.z - hr.z * vi.z;
                are1 += hr.w * vr.w + hi.w * vi.w;
                aim1 += hi.w * vr.w - hr.w * vi.w;
            }
        }
    }

    // ---- finish both batches; per-batch trees identical to v7, interleaved ----
    float t0 = nsq0, t1 = nsq1;
    #pragma unroll
    for (int m = 1; m < 64; m <<= 1) {
        t0 += __shfl_xor(t0, m, 64);
        t1 += __shfl_xor(t1, m, 64);
    }
    const float normsq0 = t0, normsq1 = t1;

    const float Iall0 = are0 * are0 + aim0 * aim0;
    const float Iall1 = are1 * are1 + aim1 * aim1;

    const float diag0 = __shfl(Iall0, ui * 9, 64);
    const float diag1 = __shfl(Iall1, ui * 9, 64);
    float r0 = Iall0, r1 = Iall1;
    r0 += __shfl_xor(r0, 1, 64);  r1 += __shfl_xor(r1, 1, 64);
    r0 += __shfl_xor(r0, 2, 64);  r1 += __shfl_xor(r1, 2, 64);
    r0 += __shfl_xor(r0, 4, 64);  r1 += __shfl_xor(r1, 4, 64);

    const float Ip0   = r0 - diag0;
    const float Ip1   = r1 - diag1;
    const float S0    = (8.0f / normsq0) * diag0;
    const float S1    = (8.0f / normsq1) * diag1;
    const float SINR0 = S0 / (Ip0 + Nval);
    const float SINR1 = S1 / (Ip1 + Nval);
    const float R0    = hw_log2(1.0f + SINR0);
    const float R1    = hw_log2(1.0f + SINR1);

    // same accumulation order as v7 (batch b0 then b1)
    lane_sumR += R0;
    lane_sumR += R1;
    lane_sumf += hw_exp2((T_THRESH - R0) * LOG2_10) - R0;
    lane_sumf += hw_exp2((T_THRESH - R1) * LOG2_10) - R1;

    // ---- block-level reduction (identical to v7) ----
    float wf = lane_sumf;
    #pragma unroll
    for (int m = 1; m < 64; m <<= 1) wf += __shfl_xor(wf, m, 64);
    wf *= 0.125f;                                        // each user counted 8x
    if (lane == 0) red_f[wave] = wf;
    if (uj == 0)   red_R[wave][ui] = lane_sumR;
    __syncthreads();

    if (tid < U_) {
        float s = 0.0f;
        #pragma unroll
        for (int w = 0; w < WPB_; ++w) s += red_R[w][tid];
        partial[blockIdx.x * 9 + 1 + tid] = s;
    } else if (tid == U_) {
        float s = 0.0f;
        #pragma unroll
        for (int w = 0; w < WPB_; ++w) s += red_f[w];
        partial[blockIdx.x * 9] = s;
    }
}

__global__ __launch_bounds__(1024) void se_final(const float* __restrict__ partial,
                                                 float* __restrict__ out) {
    // 2048 partial rows: each of 1024 threads folds 2 rows, then
    // deterministic wave trees + fixed cross-wave order (no atomics).
    __shared__ float acc[16][9];
    const int tid = threadIdx.x, w = tid >> 6, l = tid & 63;

    float v[9];
    #pragma unroll
    for (int s = 0; s < 9; ++s)
        v[s] = partial[tid * 9 + s] + partial[(tid + 1024) * 9 + s];

    #pragma unroll
    for (int s = 0; s < 9; ++s) {
        float t = v[s];
        #pragma unroll
        for (int m = 1; m < 64; m <<= 1) t += __shfl_xor(t, m, 64);
        if (l == 0) acc[w][s] = t;
    }
    __syncthreads();

    if (tid == 0) {
        float sums[9];
        #pragma unroll
        for (int s = 0; s < 9; ++s) {
            float t = acc[0][s];
            #pragma unroll
            for (int ww = 1; ww < 16; ++ww) t += acc[ww][s];
            sums[s] = t;
        }
        const float inv = 1.0f / (float)B_;
        out[0] = sums[0] * inv;          // mean(Rp)
        float tot = 0.0f;
        #pragma unroll
        for (int i = 0; i < U_; ++i) {
            const float r = sums[1 + i] * inv;
            out[1 + i] = r;              // R_per_user_p
            tot += r;
        }
        out[9] = tot;                    // sum(R_per_user_p)
    }
}

extern "C" void kernel_launch(void* const* d_in, const int* in_sizes, int n_in,
                              void* d_out, int out_size, void* d_ws, size_t ws_size,
                              hipStream_t stream) {
    const float* h  = (const float*)d_in[0];
    const float* v  = (const float*)d_in[1];
    const float* Np = (const float*)d_in[2];
    float* out      = (float*)d_out;
    float* partial  = (float*)d_ws;   // NBLK_*9 floats (73728 B), fully overwritten each call

    se_main<<<NBLK_, 256, 0, stream>>>(h, v, Np, partial);
    se_final<<<1, 1024, 0, stream>>>(partial, out);
}

// Round 10
// 177.639 us; speedup vs baseline: 1.1630x; 1.1630x over previous
//
#include <hip/hip_runtime.h>

// SE_loss_w_threshold: h,v (8,16384,128) fp32, N scalar.
// out[0]=mean(Rp), out[1..8]=R_per_user_p, out[9]=sum(R_per_user_p)
//
// v10: all-upfront DMA staging, one memory stall per wave.
//   v9 post-mortem: k-loop interleave spilled (VGPR=64 cap, WRITE 102MB).
//   Cross-round accounting: per-CU LDS work = ~63Kcy (26us floor), VALU
//   ~30Kcy, memory overlappable -- yet wall = 120Kcy at LDS 47% busy.
//   => packing-bound: 4 serial {stage->wait->compute} phases per wave
//   starve the LDS pipe at every boundary (v8 kept the same boundaries).
//   Fix: issue ALL 16 global_load_lds DMAs (2 batches x h,v x 4 instrs)
//   at wave start -- zero VGPR cost, 16KB/wave LDS -- then counted gates:
//   vmcnt(8) before batch0 compute (batch1's DMAs fly underneath),
//   vmcnt(0) before batch1. One stall point per wave; rest is pure
//   LDS+VALU. ds_writes eliminated (82 -> 74 LDS ops/batch).
//   Banks: v8's proven source-rotation, 16 slots: row r=2u+p holds global
//   chunk g at slot (g+u)&15; reads at slot (c+u)&15 -> 8 distinct bank
//   groups x 8-lane broadcast = conflict-free. nsq readback in v7's exact
//   order (4 reads/wave, ~8-way conflicted, cheap -- v8-proven).
//   LDS = exactly 64KB/block (2 blocks/CU, 8 waves/CU -- occupancy never
//   moved the wall in v1/v7). Reduction scratch OVERLAYS tiles after a
//   block-wide barrier.
// All accumulation orders (staging values, nsq chunk order, A-loop k
// ascending, per-batch trees, b0-then-b1 sums) bit-identical to v7/v9
// => absmax 0.0 expected.

constexpr int U_    = 8;
constexpr int B_    = 16384;
constexpr int NT_   = 128;
constexpr int NBLK_ = 2048;
constexpr int WPB_  = 4;              // waves per block (256 threads)
constexpr int TW_   = NBLK_ * WPB_;   // 8192 waves; 2 batches per wave
constexpr size_t UST_ = (size_t)B_ * NT_;  // user stride (floats)
constexpr float T_THRESH = 0.3f;
constexpr float LOG2_10  = 3.3219280948873623f;

typedef __attribute__((address_space(3))) void lds_void;
typedef const __attribute__((address_space(1))) void g_void;

__device__ __forceinline__ void gload16(const float* g, float* l) {
    // 16B/lane DMA: global (per-lane addr) -> LDS (wave-uniform base + lane*16)
    __builtin_amdgcn_global_load_lds((g_void*)g, (lds_void*)l, 16, 0, 0);
}

__device__ __forceinline__ float hw_log2(float x) { return __builtin_amdgcn_logf(x); }
__device__ __forceinline__ float hw_exp2(float x) { return __builtin_amdgcn_exp2f(x); }

__global__ __launch_bounds__(256, 4) void se_main(const float* __restrict__ h,
                                                  const float* __restrict__ vv,
                                                  const float* __restrict__ Np,
                                                  float* __restrict__ partial) {
    // 64KB exactly: [wave][batch][h/v][16 plane-rows x 64 floats, linear].
    // plane-row r = 2*user + {0:re,1:im}; slot s (16B) holds global chunk
    // (s - u) & 15  (source-rotated).
    __shared__ __align__(16) float lds[WPB_][2][2][1024];

    const int tid  = threadIdx.x;
    const int wave = tid >> 6;
    const int lane = tid & 63;
    const int ui   = lane >> 3;   // user i (row of A)
    const int uj   = lane & 7;    // user j (col of A)
    const float Nval = Np[0];

    const int gwave = blockIdx.x * WPB_ + wave;
    const int b0 = gwave;             // batch 0 (== v7's it=0)
    const int b1 = gwave + TW_;       // batch 1 (== v7's it=1)

    float (*T0)[1024] = lds[wave][0];   // [h/v][1024]
    float (*T1)[1024] = lds[wave][1];

    // ---- per-lane DMA source offsets; instr q covers users 2q, 2q+1 ----
    size_t off[4];
    #pragma unroll
    for (int q = 0; q < 4; ++q) {
        const int u = 2 * q + (lane >> 5);   // user
        const int p = (lane >> 4) & 1;       // 0=re plane, 1=im plane
        const int s = lane & 15;             // dest slot
        const int g = (s - u) & 15;          // source chunk (rotation u)
        off[q] = (size_t)u * UST_ + (size_t)(p * 64 + g * 4);
    }

    // ---- issue ALL 16 DMAs: batch0's 8 first, then batch1's 8 ----
    #pragma unroll
    for (int q = 0; q < 4; ++q) {
        gload16(h  + off[q] + (size_t)b0 * NT_, &T0[0][q * 256]);
        gload16(vv + off[q] + (size_t)b0 * NT_, &T0[1][q * 256]);
    }
    #pragma unroll
    for (int q = 0; q < 4; ++q) {
        gload16(h  + off[q] + (size_t)b1 * NT_, &T1[0][q * 256]);
        gload16(vv + off[q] + (size_t)b1 * NT_, &T1[1][q * 256]);
    }

    float nsq0 = 0.0f, are0 = 0.0f, aim0 = 0.0f;
    float nsq1 = 0.0f, are1 = 0.0f, aim1 = 0.0f;

    // ---- batch 0: wait only for its own 8 DMAs (batch 1's still fly) ----
    asm volatile("s_waitcnt vmcnt(8)" ::: "memory");
    __builtin_amdgcn_sched_barrier(0);
    {
        const float* ht = T0[0];
        const float* vt = T0[1];
        // nsq in v7 order: chunk uj (re then im), then chunk 8+uj (re then im)
        {
            const int s0 = ((uj + ui) & 15) * 4;
            const int s1 = ((8 + uj + ui) & 15) * 4;
            const float4 a = *reinterpret_cast<const float4*>(vt + (2 * ui) * 64 + s0);
            const float4 b = *reinterpret_cast<const float4*>(vt + (2 * ui + 1) * 64 + s0);
            const float4 c = *reinterpret_cast<const float4*>(vt + (2 * ui) * 64 + s1);
            const float4 d = *reinterpret_cast<const float4*>(vt + (2 * ui + 1) * 64 + s1);
            nsq0 += a.x * a.x + a.y * a.y + a.z * a.z + a.w * a.w
                  + b.x * b.x + b.y * b.y + b.z * b.z + b.w * b.w;
            nsq0 += c.x * c.x + c.y * c.y + c.z * c.z + c.w * c.w
                  + d.x * d.x + d.y * d.y + d.z * d.z + d.w * d.w;
        }
        const float* ha = ht + (2 * ui) * 64;
        const float* va = vt + (2 * uj) * 64;
        #pragma unroll
        for (int c = 0; c < 16; ++c) {       // global k = 4c..4c+3, ascending
            const int hs = ((c + ui) & 15) * 4;
            const int vs = ((c + uj) & 15) * 4;
            const float4 hr = *reinterpret_cast<const float4*>(ha + hs);
            const float4 hi = *reinterpret_cast<const float4*>(ha + 64 + hs);
            const float4 vr = *reinterpret_cast<const float4*>(va + vs);
            const float4 vi = *reinterpret_cast<const float4*>(va + 64 + vs);
            are0 += hr.x * vr.x + hi.x * vi.x;
            aim0 += hi.x * vr.x - hr.x * vi.x;
            are0 += hr.y * vr.y + hi.y * vi.y;
            aim0 += hi.y * vr.y - hr.y * vi.y;
            are0 += hr.z * vr.z + hi.z * vi.z;
            aim0 += hi.z * vr.z - hr.z * vi.z;
            are0 += hr.w * vr.w + hi.w * vi.w;
            aim0 += hi.w * vr.w - hr.w * vi.w;
        }
    }

    // ---- batch 1 ----
    asm volatile("s_waitcnt vmcnt(0)" ::: "memory");
    __builtin_amdgcn_sched_barrier(0);
    {
        const float* ht = T1[0];
        const float* vt = T1[1];
        {
            const int s0 = ((uj + ui) & 15) * 4;
            const int s1 = ((8 + uj + ui) & 15) * 4;
            const float4 a = *reinterpret_cast<const float4*>(vt + (2 * ui) * 64 + s0);
            const float4 b = *reinterpret_cast<const float4*>(vt + (2 * ui + 1) * 64 + s0);
            const float4 c = *reinterpret_cast<const float4*>(vt + (2 * ui) * 64 + s1);
            const float4 d = *reinterpret_cast<const float4*>(vt + (2 * ui + 1) * 64 + s1);
            nsq1 += a.x * a.x + a.y * a.y + a.z * a.z + a.w * a.w
                  + b.x * b.x + b.y * b.y + b.z * b.z + b.w * b.w;
            nsq1 += c.x * c.x + c.y * c.y + c.z * c.z + c.w * c.w
                  + d.x * d.x + d.y * d.y + d.z * d.z + d.w * d.w;
        }
        const float* ha = ht + (2 * ui) * 64;
        const float* va = vt + (2 * uj) * 64;
        #pragma unroll
        for (int c = 0; c < 16; ++c) {
            const int hs = ((c + ui) & 15) * 4;
            const int vs = ((c + uj) & 15) * 4;
            const float4 hr = *reinterpret_cast<const float4*>(ha + hs);
            const float4 hi = *reinterpret_cast<const float4*>(ha + 64 + hs);
            const float4 vr = *reinterpret_cast<const float4*>(va + vs);
            const float4 vi = *reinterpret_cast<const float4*>(va + 64 + vs);
            are1 += hr.x * vr.x + hi.x * vi.x;
            aim1 += hi.x * vr.x - hr.x * vi.x;
            are1 += hr.y * vr.y + hi.y * vi.y;
            aim1 += hi.y * vr.y - hr.y * vi.y;
            are1 += hr.z * vr.z + hi.z * vi.z;
            aim1 += hi.z * vr.z - hr.z * vi.z;
            are1 += hr.w * vr.w + hi.w * vi.w;
            aim1 += hi.w * vr.w - hr.w * vi.w;
        }
    }

    // ---- finish both batches; per-batch trees identical to v7, interleaved (v9) ----
    float t0 = nsq0, t1 = nsq1;
    #pragma unroll
    for (int m = 1; m < 64; m <<= 1) {
        t0 += __shfl_xor(t0, m, 64);
        t1 += __shfl_xor(t1, m, 64);
    }
    const float normsq0 = t0, normsq1 = t1;

    const float Iall0 = are0 * are0 + aim0 * aim0;
    const float Iall1 = are1 * are1 + aim1 * aim1;

    const float diag0 = __shfl(Iall0, ui * 9, 64);
    const float diag1 = __shfl(Iall1, ui * 9, 64);
    float r0 = Iall0, r1 = Iall1;
    r0 += __shfl_xor(r0, 1, 64);  r1 += __shfl_xor(r1, 1, 64);
    r0 += __shfl_xor(r0, 2, 64);  r1 += __shfl_xor(r1, 2, 64);
    r0 += __shfl_xor(r0, 4, 64);  r1 += __shfl_xor(r1, 4, 64);

    const float Ip0   = r0 - diag0;
    const float Ip1   = r1 - diag1;
    const float S0    = (8.0f / normsq0) * diag0;
    const float S1    = (8.0f / normsq1) * diag1;
    const float SINR0 = S0 / (Ip0 + Nval);
    const float SINR1 = S1 / (Ip1 + Nval);
    const float R0    = hw_log2(1.0f + SINR0);
    const float R1    = hw_log2(1.0f + SINR1);

    float lane_sumR = R0 + R1;   // same order as v7/v9 (b0 then b1)
    float lane_sumf = (hw_exp2((T_THRESH - R0) * LOG2_10) - R0)
                    + (hw_exp2((T_THRESH - R1) * LOG2_10) - R1);

    float wf = lane_sumf;
    #pragma unroll
    for (int m = 1; m < 64; m <<= 1) wf += __shfl_xor(wf, m, 64);
    wf *= 0.125f;                // each user counted 8x

    // ---- block reduction: overlay scratch onto the (now dead) tiles ----
    __syncthreads();             // all waves done reading their tiles
    float* red = &lds[0][0][0][0];   // red[0..3]=wf per wave; red[4+w*8+u]=sumR
    if (lane == 0) red[wave] = wf;
    if (uj == 0)   red[4 + wave * 8 + ui] = lane_sumR;
    __syncthreads();

    if (tid < U_) {
        float s = 0.0f;
        #pragma unroll
        for (int w = 0; w < WPB_; ++w) s += red[4 + w * 8 + tid];
        partial[blockIdx.x * 9 + 1 + tid] = s;
    } else if (tid == U_) {
        float s = 0.0f;
        #pragma unroll
        for (int w = 0; w < WPB_; ++w) s += red[w];
        partial[blockIdx.x * 9] = s;
    }
}

__global__ __launch_bounds__(1024) void se_final(const float* __restrict__ partial,
                                                 float* __restrict__ out) {
    // 2048 partial rows: each of 1024 threads folds 2 rows, then
    // deterministic wave trees + fixed cross-wave order (no atomics).
    __shared__ float acc[16][9];
    const int tid = threadIdx.x, w = tid >> 6, l = tid & 63;

    float v[9];
    #pragma unroll
    for (int s = 0; s < 9; ++s)
        v[s] = partial[tid * 9 + s] + partial[(tid + 1024) * 9 + s];

    #pragma unroll
    for (int s = 0; s < 9; ++s) {
        float t = v[s];
        #pragma unroll
        for (int m = 1; m < 64; m <<= 1) t += __shfl_xor(t, m, 64);
        if (l == 0) acc[w][s] = t;
    }
    __syncthreads();

    if (tid == 0) {
        float sums[9];
        #pragma unroll
        for (int s = 0; s < 9; ++s) {
            float t = acc[0][s];
            #pragma unroll
            for (int ww = 1; ww < 16; ++ww) t += acc[ww][s];
            sums[s] = t;
        }
        const float inv = 1.0f / (float)B_;
        out[0] = sums[0] * inv;          // mean(Rp)
        float tot = 0.0f;
        #pragma unroll
        for (int i = 0; i < U_; ++i) {
            const float r = sums[1 + i] * inv;
            out[1 + i] = r;              // R_per_user_p
            tot += r;
        }
        out[9] = tot;                    // sum(R_per_user_p)
    }
}

extern "C" void kernel_launch(void* const* d_in, const int* in_sizes, int n_in,
                              void* d_out, int out_size, void* d_ws, size_t ws_size,
                              hipStream_t stream) {
    const float* h  = (const float*)d_in[0];
    const float* v  = (const float*)d_in[1];
    const float* Np = (const float*)d_in[2];
    float* out      = (float*)d_out;
    float* partial  = (float*)d_ws;   // NBLK_*9 floats (73728 B), fully overwritten each call

    se_main<<<NBLK_, 256, 0, stream>>>(h, v, Np, partial);
    se_final<<<1, 1024, 0, stream>>>(partial, out);
}